// Round 6
// baseline (532.560 us; speedup 1.0000x reference)
//
#include <hip/hip_runtime.h>
#include <math.h>
#include <stdint.h>

#define HDIM 128
#define TM 256  // edges per block (8 waves, 32 edges per wave)

typedef short s16x8 __attribute__((ext_vector_type(8)));      // 8 bf16 (4 VGPRs) MFMA A/B frag
typedef float f32x4 __attribute__((ext_vector_type(4)));      // MFMA C/D frag
typedef unsigned short ushort8 __attribute__((ext_vector_type(8)));

// fp32 -> bf16 round-to-nearest-even
__device__ __forceinline__ unsigned short f2bf(float x) {
    unsigned u = __float_as_uint(x);
    u += 0x7FFFu + ((u >> 16) & 1u);
    return (unsigned short)(u >> 16);
}

// Abramowitz-Stegun 7.1.26: |err| <= 1.5e-7 absolute.
__device__ __forceinline__ float erf_fast(float x) {
    float ax = fabsf(x);
    float t = __builtin_amdgcn_rcpf(fmaf(0.3275911f, ax, 1.0f));
    float p =        fmaf(t, 1.061405429f, -1.453152027f);
    p = fmaf(t, p, 1.421413741f);
    p = fmaf(t, p, -0.284496736f);
    p = fmaf(t, p, 0.254829592f);
    float e = exp2f(ax * ax * -1.4426950408889634f);
    float r = 1.0f - p * t * e;
    return copysignf(r, x);
}

__device__ __forceinline__ float gelu_exact(float x) {
    return 0.5f * x * (1.0f + erf_fast(x * 0.70710678118654752440f));
}

// async global->LDS 16B per lane; LDS layout must be linear (wave-uniform base + lane*16)
__device__ __forceinline__ void async_cp16(void* lds_dst, const void* g_src) {
    __builtin_amdgcn_global_load_lds(
        (const __attribute__((address_space(1))) unsigned int*)g_src,
        (__attribute__((address_space(3))) unsigned int*)lds_dst,
        16, 0, 0);
}

// ---------------- stable counting-sort: scan + scatter ----------------

__global__ void k_scan(const int* __restrict__ counts, int nChunks,
                       int* __restrict__ bbase, int* __restrict__ gstart, int E) {
    __shared__ int tot[3];
    int t = threadIdx.x;         // block = 192
    int lane = t & 63;
    int g = t >> 6;              // 0..2
    int carry = 0;
    for (int base = 0; base < nChunks; base += 64) {
        int b = base + lane;
        int v = (b < nChunks) ? counts[b * 3 + g] : 0;
        int sc = v;
        #pragma unroll
        for (int off = 1; off < 64; off <<= 1) {
            int u = __shfl_up(sc, off);
            if (lane >= off) sc += u;
        }
        if (b < nChunks) bbase[b * 3 + g] = carry + sc - v;
        carry += __shfl(sc, 63);
    }
    if (lane == 0) tot[g] = carry;
    __syncthreads();
    if (t == 0) {
        gstart[0] = 0;
        gstart[1] = tot[0];
        gstart[2] = tot[0] + tot[1];
        gstart[3] = E;
    }
}

__global__ void k_scatter(const int* __restrict__ groups, int E,
                          const int* __restrict__ bbase, const int* __restrict__ gstart,
                          int* __restrict__ sorted) {
    int b = blockIdx.x;
    int lane = threadIdx.x;  // block = 64 (one wave)
    int run0 = gstart[0] + bbase[b * 3 + 0];
    int run1 = gstart[1] + bbase[b * 3 + 1];
    int run2 = gstart[2] + bbase[b * 3 + 2];
    unsigned long long lt = (1ull << lane) - 1ull;
    for (int p = 0; p < 16; ++p) {
        int e = b * 1024 + p * 64 + lane;
        int g = (e < E) ? groups[e] : 3;
        unsigned long long m0 = __ballot(g == 0);
        unsigned long long m1 = __ballot(g == 1);
        unsigned long long m2 = __ballot(g == 2);
        int pos = 0;
        if (g == 0) pos = run0 + __popcll(m0 & lt);
        else if (g == 1) pos = run1 + __popcll(m1 & lt);
        else if (g == 2) pos = run2 + __popcll(m2 & lt);
        if (e < E) sorted[pos] = e;
        run0 += __popcll(m0);
        run1 += __popcll(m1);
        run2 += __popcll(m2);
    }
}

// ---------------- prep (fused with histogram) ----------------
// Block ranges: [0, embBlocks): emb fp32->bf16.  [embBlocks, +60): W1/W2 convert.
// [embBlocks+60, +nChunks): per-1024-edge group histogram.
// W1S[g][n][gk'*8..+7], gk' = gk ^ (n&7)  (bank swizzle for LDS b128 reads).
// W2T[g][n=64][k=128].
__global__ void k_prep(const float* __restrict__ emb, int embElems, int embBlocks,
                       const float* __restrict__ W1, const float* __restrict__ W2,
                       unsigned short* __restrict__ embB,
                       unsigned short* __restrict__ W1S, unsigned short* __restrict__ W2T,
                       const int* __restrict__ groups, int E, int* __restrict__ counts) {
    if ((int)blockIdx.x >= embBlocks + 60) {
        // histogram part
        __shared__ int c[3];
        int t = threadIdx.x;
        int blk = blockIdx.x - (embBlocks + 60);
        if (t < 3) c[t] = 0;
        __syncthreads();
        int base = blk * 1024;
        for (int i = t; i < 1024; i += 256) {
            int e = base + i;
            if (e < E) atomicAdd(&c[groups[e]], 1);
        }
        __syncthreads();
        if (t < 3) counts[blk * 3 + t] = c[t];
        return;
    }
    if ((int)blockIdx.x < embBlocks) {
        int i = (blockIdx.x * 256 + threadIdx.x) * 8;
        if (i + 8 <= embElems) {
            float4 a = *(const float4*)(emb + i);
            float4 b = *(const float4*)(emb + i + 4);
            ushort8 o;
            o[0] = f2bf(a.x); o[1] = f2bf(a.y); o[2] = f2bf(a.z); o[3] = f2bf(a.w);
            o[4] = f2bf(b.x); o[5] = f2bf(b.y); o[6] = f2bf(b.z); o[7] = f2bf(b.w);
            *(ushort8*)(embB + i) = o;
        } else {
            for (int j = i; j < embElems; ++j) embB[j] = f2bf(emb[j]);
        }
        return;
    }
    int idx = (blockIdx.x - embBlocks) * 256 + threadIdx.x;
    if (idx < 3 * 32 * 128) {                    // W1S: task = (g, gk, n)
        int g  = idx >> 12;
        int r  = idx & 4095;
        int gk = r >> 7;                         // k-granule 0..31 (k0 = gk*8)
        int n  = r & 127;
        const float* src = W1 + ((size_t)g * 256 + gk * 8) * 128 + n;
        ushort8 o;
        #pragma unroll
        for (int j = 0; j < 8; ++j) o[j] = f2bf(src[j * 128]);
        int gks = gk ^ (n & 7);                  // bank swizzle
        *(ushort8*)(W1S + ((size_t)(g * 128 + n)) * 256 + gks * 8) = o;
    } else if (idx < 3 * 32 * 128 + 3 * 16 * 64) {
        int r2 = idx - 3 * 32 * 128;             // W2T[g][n=64][k=128]
        int g  = r2 >> 10;
        int r  = r2 & 1023;
        int kc = r >> 6;
        int n  = r & 63;
        const float* src = W2 + (size_t)g * 128 * 64 + (size_t)(kc * 8) * 64 + n;
        ushort8 o;
        #pragma unroll
        for (int j = 0; j < 8; ++j) o[j] = f2bf(src[j * 64]);
        *(ushort8*)(W2T + ((size_t)(g * 64 + n)) * 128 + kc * 8) = o;
    }
}

// ---------------- fused per-edge MLP (MFMA bf16, LDS-staged W1) ----------------
// Block: 512 thr = 8 waves; TM=256 edges, 32 per wave (2 m-tiles of 16).
// A-frags: preloaded into registers before the group loop.
// GEMM1 B: W1S[g] staged once to LDS (64KB) via global_load_lds (ONE vmcnt drain).
// sH (swizzled 256x128 bf16 = 64KB exact) overlays the dead W1s region.
// GEMM2 B: global W2T (16KB/group, L1-resident). 64KB LDS -> 2 blocks/CU = 16 waves/CU.
__global__ __launch_bounds__(512, 3)
void k_mlp(const unsigned short* __restrict__ embB,
           const int* __restrict__ edges,
           const int* __restrict__ sorted,
           const int* __restrict__ gstart,
           const unsigned short* __restrict__ W1S,
           const float* __restrict__ b1,
           const float* __restrict__ lng, const float* __restrict__ lnb,
           const unsigned short* __restrict__ W2T,
           const float* __restrict__ b2,
           const float* __restrict__ W3, const float* __restrict__ b3,
           float* __restrict__ out, int E)
{
    __shared__ __align__(16) unsigned short smem[32768];   // 65536 B
    unsigned short* W1s = smem;                 // [128][256] bf16, swizzled
    unsigned short* sH  = smem;                 // [256][128] bf16 swizzled, after GEMM1

    const int t    = threadIdx.x;
    const int w    = t >> 6;        // wave 0..7
    const int lane = t & 63;
    const int n0   = lane & 15;     // MFMA 16-index
    const int quad = lane >> 4;     // MFMA k-quad / D row-group

    const int pos0 = blockIdx.x * TM;

    int gs1 = gstart[1], gs2 = gstart[2];
    int plast = (pos0 + TM - 1 < E) ? pos0 + TM - 1 : E - 1;
    int g0 = (pos0  >= gs2) ? 2 : (pos0  >= gs1) ? 1 : 0;
    int g1 = (plast >= gs2) ? 2 : (plast >= gs1) ? 1 : 0;

    // ---- prefetch all A-fragments into registers (held across the g-loop) ----
    const unsigned short* urow[2];
    const unsigned short* vrow[2];
    #pragma unroll
    for (int mt = 0; mt < 2; ++mt) {
        int p = pos0 + w * 32 + mt * 16 + n0;
        int pc = p < E ? p : E - 1;
        int e  = sorted[pc];
        urow[mt] = embB + (size_t)edges[2 * e]     * HDIM;
        vrow[mt] = embB + (size_t)edges[2 * e + 1] * HDIM;
    }
    s16x8 afr[8][2];
    #pragma unroll
    for (int ks = 0; ks < 8; ++ks)
        #pragma unroll
        for (int mt = 0; mt < 2; ++mt)
            afr[ks][mt] = *(const s16x8*)((ks < 4 ? urow[mt] : vrow[mt]) + ((ks * 32) & (HDIM - 1)) + quad * 8);

    for (int g = g0; g <= g1; ++g) {
        // ---- stage W1S[g] (64KB) into LDS: 512 thr x 16B x 8 ----
        {
            const unsigned char* src = (const unsigned char*)(W1S + (size_t)g * 128 * 256);
            #pragma unroll
            for (int r = 0; r < 8; ++r) {
                int off = r * 8192 + t * 16;
                async_cp16((unsigned char*)smem + off, src + off);
            }
        }

        // hoist epilogue constants (overlap staging)
        float b1v[8], lgv[8], lbv[8];
        #pragma unroll
        for (int nt = 0; nt < 8; ++nt) {
            int c = nt * 16 + n0;
            b1v[nt] = b1[g * HDIM + c];
            lgv[nt] = lng[g * HDIM + c];
            lbv[nt] = lnb[g * HDIM + c];
        }
        float b2v[4], w3v[4];
        #pragma unroll
        for (int nt2 = 0; nt2 < 4; ++nt2) {
            int c = nt2 * 16 + n0;
            b2v[nt2] = b2[g * 64 + c];
            w3v[nt2] = W3[g * 64 + c];
        }
        float bias3 = b3[g];

        __syncthreads();   // ONE drain: staging (+ first-iter A-frags)

        // ---- GEMM1: [256 x 256] x [256 x 128], B from LDS ----
        f32x4 acc[2][8];
        #pragma unroll
        for (int mt = 0; mt < 2; ++mt)
            #pragma unroll
            for (int nt = 0; nt < 8; ++nt) acc[mt][nt] = (f32x4){0.f, 0.f, 0.f, 0.f};

        #pragma unroll
        for (int ks = 0; ks < 8; ++ks) {
            #pragma unroll
            for (int nt = 0; nt < 8; ++nt) {
                int gk = (ks * 4 + quad) ^ (n0 & 7);          // de-swizzle
                s16x8 bfrag = *(const s16x8*)(&W1s[(nt * 16 + n0) * 256 + gk * 8]);
                acc[0][nt] = __builtin_amdgcn_mfma_f32_16x16x32_bf16(afr[ks][0], bfrag, acc[0][nt], 0, 0, 0);
                acc[1][nt] = __builtin_amdgcn_mfma_f32_16x16x32_bf16(afr[ks][1], bfrag, acc[1][nt], 0, 0, 0);
            }
        }
        __syncthreads();   // W1s dead; sH region becomes writable

        // ---- bias + LayerNorm + GELU; D layout: row = quad*4+reg, col = nt*16+n0 ----
        #pragma unroll
        for (int mt = 0; mt < 2; ++mt) {
            #pragma unroll
            for (int reg = 0; reg < 4; ++reg) {
                float s = 0.f, s2 = 0.f;
                float xv[8];
                #pragma unroll
                for (int nt = 0; nt < 8; ++nt) {
                    float x = acc[mt][nt][reg] + b1v[nt];
                    xv[nt] = x; s += x; s2 += x * x;
                }
                #pragma unroll
                for (int off = 1; off < 16; off <<= 1) {
                    s  += __shfl_xor(s,  off);
                    s2 += __shfl_xor(s2, off);
                }
                float mu  = s  * (1.0f / HDIM);
                float var = s2 * (1.0f / HDIM) - mu * mu;
                float rs  = rsqrtf(var + 1e-5f);
                int m  = w * 32 + mt * 16 + quad * 4 + reg;
                int mx = m & 7;
                #pragma unroll
                for (int nt = 0; nt < 8; ++nt) {
                    float x = (xv[nt] - mu) * rs * lgv[nt] + lbv[nt];
                    x = gelu_exact(x);
                    // swizzled store: col granule ^ (m&7)
                    int gsw = ((nt * 2 + (n0 >> 3)) ^ mx) << 3;
                    sH[m * 128 + gsw + (n0 & 7)] = f2bf(x);
                }
            }
        }
        __syncthreads();

        // ---- GEMM2: h[256x128] x W2T[g][n=64][k=128], A from swizzled sH ----
        const unsigned short* W2Tg = W2T + (size_t)g * 64 * 128;
        f32x4 acc2[2][4];
        #pragma unroll
        for (int mt = 0; mt < 2; ++mt)
            #pragma unroll
            for (int nt2 = 0; nt2 < 4; ++nt2) acc2[mt][nt2] = (f32x4){0.f, 0.f, 0.f, 0.f};

        #pragma unroll
        for (int ks2 = 0; ks2 < 4; ++ks2) {
            s16x8 a2[2];
            #pragma unroll
            for (int mt = 0; mt < 2; ++mt) {
                int m = w * 32 + mt * 16 + n0;
                a2[mt] = *(const s16x8*)(&sH[m * 128 + (((ks2 * 4 + quad) ^ (m & 7)) << 3)]);
            }
            #pragma unroll
            for (int nt2 = 0; nt2 < 4; ++nt2) {
                s16x8 b2f = *(const s16x8*)(W2Tg + (size_t)(nt2 * 16 + n0) * 128 + ks2 * 32 + quad * 8);
                #pragma unroll
                for (int mt = 0; mt < 2; ++mt)
                    acc2[mt][nt2] = __builtin_amdgcn_mfma_f32_16x16x32_bf16(a2[mt], b2f, acc2[mt][nt2], 0, 0, 0);
            }
        }

        // ---- epilogue: GELU + dot W3 + quad reduce + write ----
        {
            int lo = (g == 0) ? 0   : (g == 1) ? gs1 : gs2;
            int hi = (g == 0) ? gs1 : (g == 1) ? gs2 : E;
            #pragma unroll
            for (int mt = 0; mt < 2; ++mt) {
                #pragma unroll
                for (int reg = 0; reg < 4; ++reg) {
                    float sacc = 0.f;
                    #pragma unroll
                    for (int nt2 = 0; nt2 < 4; ++nt2)
                        sacc += gelu_exact(acc2[mt][nt2][reg] + b2v[nt2]) * w3v[nt2];
                    #pragma unroll
                    for (int off = 1; off < 16; off <<= 1)
                        sacc += __shfl_xor(sacc, off);
                    if (n0 == 0) {
                        int p = pos0 + w * 32 + mt * 16 + quad * 4 + reg;
                        if (p >= lo && p < hi) out[p] = sacc + bias3;
                    }
                }
            }
        }
        __syncthreads();   // sH dead before next group's staging
    }
}

extern "C" void kernel_launch(void* const* d_in, const int* in_sizes, int n_in,
                              void* d_out, int out_size, void* d_ws, size_t ws_size,
                              hipStream_t stream) {
    const float* emb    = (const float*)d_in[0];
    const int*   edges  = (const int*)  d_in[1];
    const int*   groups = (const int*)  d_in[2];
    const float* W1     = (const float*)d_in[3];
    const float* b1     = (const float*)d_in[4];
    const float* lng    = (const float*)d_in[5];
    const float* lnb    = (const float*)d_in[6];
    const float* W2     = (const float*)d_in[7];
    const float* b2     = (const float*)d_in[8];
    const float* W3     = (const float*)d_in[9];
    const float* b3     = (const float*)d_in[10];
    float* out = (float*)d_out;
    int E        = in_sizes[2];
    int embElems = in_sizes[0];

    int nChunks = (E + 1023) / 1024;
    int embBlocks = (embElems / 8 + 255) / 256;

    // workspace layout
    unsigned short* embB = (unsigned short*)d_ws;
    unsigned short* W1S  = embB + (((size_t)embElems + 7) & ~(size_t)7);
    unsigned short* W2T  = W1S + (size_t)3 * 128 * 256;
    int* counts = (int*)(W2T + (size_t)3 * 64 * 128);
    int* bbase  = counts + (size_t)nChunks * 3;
    int* gstart = bbase  + (size_t)nChunks * 3;
    int* sorted = gstart + 4;

    k_prep   <<<dim3(embBlocks + 60 + nChunks), dim3(256), 0, stream>>>(
        emb, embElems, embBlocks, W1, W2, embB, W1S, W2T, groups, E, counts);
    k_scan   <<<dim3(1),       dim3(192), 0, stream>>>(counts, nChunks, bbase, gstart, E);
    k_scatter<<<dim3(nChunks), dim3(64),  0, stream>>>(groups, E, bbase, gstart, sorted);

    int nTiles = (E + TM - 1) / TM;
    k_mlp<<<dim3(nTiles), dim3(512), 0, stream>>>(
        embB, edges, sorted, gstart, W1S, b1, lng, lnb, W2T, b2, W3, b3, out, E);
}

// Round 7
// 321.892 us; speedup vs baseline: 1.6545x; 1.6545x over previous
//
#include <hip/hip_runtime.h>
#include <math.h>
#include <stdint.h>

#define HDIM 128
#define TM 128  // edges per block (4 waves, 32 edges per wave)

typedef short s16x8 __attribute__((ext_vector_type(8)));      // 8 bf16 (4 VGPRs) MFMA A/B frag
typedef float f32x4 __attribute__((ext_vector_type(4)));      // MFMA C/D frag
typedef unsigned short ushort8 __attribute__((ext_vector_type(8)));

// fp32 -> bf16 round-to-nearest-even
__device__ __forceinline__ unsigned short f2bf(float x) {
    unsigned u = __float_as_uint(x);
    u += 0x7FFFu + ((u >> 16) & 1u);
    return (unsigned short)(u >> 16);
}

// Abramowitz-Stegun 7.1.26: |err| <= 1.5e-7 absolute.
__device__ __forceinline__ float erf_fast(float x) {
    float ax = fabsf(x);
    float t = __builtin_amdgcn_rcpf(fmaf(0.3275911f, ax, 1.0f));
    float p =        fmaf(t, 1.061405429f, -1.453152027f);
    p = fmaf(t, p, 1.421413741f);
    p = fmaf(t, p, -0.284496736f);
    p = fmaf(t, p, 0.254829592f);
    float e = exp2f(ax * ax * -1.4426950408889634f);
    float r = 1.0f - p * t * e;
    return copysignf(r, x);
}

__device__ __forceinline__ float gelu_exact(float x) {
    return 0.5f * x * (1.0f + erf_fast(x * 0.70710678118654752440f));
}

// 16-lane (DPP row) sum via row_ror rotations: 4 full-rate VALU adds, no LDS pipe.
template <int N>
__device__ __forceinline__ float rot_add(float v) {
    int r = __builtin_amdgcn_update_dpp(0, __float_as_int(v), 0x120 | N, 0xF, 0xF, false);
    return v + __int_as_float(r);
}
__device__ __forceinline__ float row_sum16(float v) {
    v = rot_add<1>(v); v = rot_add<2>(v); v = rot_add<4>(v); v = rot_add<8>(v);
    return v;
}

// async global->LDS 16B per lane; LDS dst must be wave-uniform base + lane*16
__device__ __forceinline__ void async_cp16(void* lds_dst, const void* g_src) {
    __builtin_amdgcn_global_load_lds(
        (const __attribute__((address_space(1))) unsigned int*)g_src,
        (__attribute__((address_space(3))) unsigned int*)lds_dst,
        16, 0, 0);
}

// ---------------- stable counting-sort: scan + scatter ----------------

__global__ void k_scan(const int* __restrict__ counts, int nChunks,
                       int* __restrict__ bbase, int* __restrict__ gstart, int E) {
    __shared__ int tot[3];
    int t = threadIdx.x;         // block = 192
    int lane = t & 63;
    int g = t >> 6;              // 0..2
    int carry = 0;
    for (int base = 0; base < nChunks; base += 64) {
        int b = base + lane;
        int v = (b < nChunks) ? counts[b * 3 + g] : 0;
        int sc = v;
        #pragma unroll
        for (int off = 1; off < 64; off <<= 1) {
            int u = __shfl_up(sc, off);
            if (lane >= off) sc += u;
        }
        if (b < nChunks) bbase[b * 3 + g] = carry + sc - v;
        carry += __shfl(sc, 63);
    }
    if (lane == 0) tot[g] = carry;
    __syncthreads();
    if (t == 0) {
        gstart[0] = 0;
        gstart[1] = tot[0];
        gstart[2] = tot[0] + tot[1];
        gstart[3] = E;
    }
}

__global__ void k_scatter(const int* __restrict__ groups, int E,
                          const int* __restrict__ bbase, const int* __restrict__ gstart,
                          int* __restrict__ sorted) {
    int b = blockIdx.x;
    int lane = threadIdx.x;  // block = 64 (one wave)
    int run0 = gstart[0] + bbase[b * 3 + 0];
    int run1 = gstart[1] + bbase[b * 3 + 1];
    int run2 = gstart[2] + bbase[b * 3 + 2];
    unsigned long long lt = (1ull << lane) - 1ull;
    for (int p = 0; p < 16; ++p) {
        int e = b * 1024 + p * 64 + lane;
        int g = (e < E) ? groups[e] : 3;
        unsigned long long m0 = __ballot(g == 0);
        unsigned long long m1 = __ballot(g == 1);
        unsigned long long m2 = __ballot(g == 2);
        int pos = 0;
        if (g == 0) pos = run0 + __popcll(m0 & lt);
        else if (g == 1) pos = run1 + __popcll(m1 & lt);
        else if (g == 2) pos = run2 + __popcll(m2 & lt);
        if (e < E) sorted[pos] = e;
        run0 += __popcll(m0);
        run1 += __popcll(m1);
        run2 += __popcll(m2);
    }
}

// ---------------- prep (fused with histogram) ----------------
// W1S layout: [g][n][half][h'][8] shorts, half = k/128, h = (k/8)%16, h' = h ^ (n&7).
// (bank swizzle so LDS b128 B-frag reads are conflict-free; rows are 256B-contiguous
//  per half so global_load_lds staging of one half is linear per row.)
// W2T[g][n=64][k=128].
__global__ void k_prep(const float* __restrict__ emb, int embElems, int embBlocks,
                       const float* __restrict__ W1, const float* __restrict__ W2,
                       unsigned short* __restrict__ embB,
                       unsigned short* __restrict__ W1S, unsigned short* __restrict__ W2T,
                       const int* __restrict__ groups, int E, int* __restrict__ counts) {
    if ((int)blockIdx.x >= embBlocks + 60) {
        // histogram part
        __shared__ int c[3];
        int t = threadIdx.x;
        int blk = blockIdx.x - (embBlocks + 60);
        if (t < 3) c[t] = 0;
        __syncthreads();
        int base = blk * 1024;
        for (int i = t; i < 1024; i += 256) {
            int e = base + i;
            if (e < E) atomicAdd(&c[groups[e]], 1);
        }
        __syncthreads();
        if (t < 3) counts[blk * 3 + t] = c[t];
        return;
    }
    if ((int)blockIdx.x < embBlocks) {
        int i = (blockIdx.x * 256 + threadIdx.x) * 8;
        if (i + 8 <= embElems) {
            float4 a = *(const float4*)(emb + i);
            float4 b = *(const float4*)(emb + i + 4);
            ushort8 o;
            o[0] = f2bf(a.x); o[1] = f2bf(a.y); o[2] = f2bf(a.z); o[3] = f2bf(a.w);
            o[4] = f2bf(b.x); o[5] = f2bf(b.y); o[6] = f2bf(b.z); o[7] = f2bf(b.w);
            *(ushort8*)(embB + i) = o;
        } else {
            for (int j = i; j < embElems; ++j) embB[j] = f2bf(emb[j]);
        }
        return;
    }
    int idx = (blockIdx.x - embBlocks) * 256 + threadIdx.x;
    if (idx < 3 * 32 * 128) {                    // W1S: task = (g, gk, n)
        int g  = idx >> 12;
        int r  = idx & 4095;
        int gk = r >> 7;                         // global k-granule 0..31 (k0 = gk*8)
        int n  = r & 127;
        const float* src = W1 + ((size_t)g * 256 + gk * 8) * 128 + n;
        ushort8 o;
        #pragma unroll
        for (int j = 0; j < 8; ++j) o[j] = f2bf(src[j * 128]);
        int half = gk >> 4;
        int hs   = (gk & 15) ^ (n & 7);          // bank swizzle within half
        *(ushort8*)(W1S + (((size_t)(g * 128 + n) * 2 + half) * 16 + hs) * 8) = o;
    } else if (idx < 3 * 32 * 128 + 3 * 16 * 64) {
        int r2 = idx - 3 * 32 * 128;             // W2T[g][n=64][k=128]
        int g  = r2 >> 10;
        int r  = r2 & 1023;
        int kc = r >> 6;
        int n  = r & 63;
        const float* src = W2 + (size_t)g * 128 * 64 + (size_t)(kc * 8) * 64 + n;
        ushort8 o;
        #pragma unroll
        for (int j = 0; j < 8; ++j) o[j] = f2bf(src[j * 64]);
        *(ushort8*)(W2T + ((size_t)(g * 64 + n)) * 128 + kc * 8) = o;
    }
}

// ---------------- fused per-edge MLP ----------------
// Block: 256 thr = 4 waves; TM=128 edges, 32 per wave (2 m-tiles of 16).
// GEMM1 K-split: stage W1 half-k (32KB) -> MFMA (u-rows) -> restage other half
// (same buffer) -> MFMA (v-rows). A-frags for each half load during that half's
// staging drain. sH (swizzled 128x128 bf16 = 32KB) overlays. Total LDS = 32KB
// -> 4 blocks/CU at <=128 VGPRs. All 16-lane reductions via DPP row_ror.
__global__ __launch_bounds__(256, 2)
void k_mlp(const unsigned short* __restrict__ embB,
           const int* __restrict__ edges,
           const int* __restrict__ sorted,
           const int* __restrict__ gstart,
           const unsigned short* __restrict__ W1S,
           const float* __restrict__ b1,
           const float* __restrict__ lng, const float* __restrict__ lnb,
           const unsigned short* __restrict__ W2T,
           const float* __restrict__ b2,
           const float* __restrict__ W3, const float* __restrict__ b3,
           float* __restrict__ out, int E)
{
    __shared__ __align__(16) unsigned short smem[16384];   // 32768 B total
    unsigned short* W1s = smem;   // [128 n][16 granule][8] per staged half
    unsigned short* sH  = smem;   // [128 m][128 c] swizzled, after GEMM1

    const int t    = threadIdx.x;
    const int w    = t >> 6;        // wave 0..3
    const int lane = t & 63;
    const int n0   = lane & 15;     // MFMA 16-index
    const int quad = lane >> 4;     // MFMA k-quad / D row-group

    const int pos0 = blockIdx.x * TM;

    int gs1 = gstart[1], gs2 = gstart[2];
    int plast = (pos0 + TM - 1 < E) ? pos0 + TM - 1 : E - 1;
    int g0 = (pos0  >= gs2) ? 2 : (pos0  >= gs1) ? 1 : 0;
    int g1 = (plast >= gs2) ? 2 : (plast >= gs1) ? 1 : 0;

    // per-lane edge rows (A-frag row m = 16w + 16mt + n0)
    const unsigned short* urow[2];
    const unsigned short* vrow[2];
    #pragma unroll
    for (int mt = 0; mt < 2; ++mt) {
        int p = pos0 + w * 32 + mt * 16 + n0;
        int pc = p < E ? p : E - 1;
        int e  = sorted[pc];
        urow[mt] = embB + (size_t)edges[2 * e]     * HDIM;
        vrow[mt] = embB + (size_t)edges[2 * e + 1] * HDIM;
    }

    for (int g = g0; g <= g1; ++g) {
        const unsigned char* W1Sg = (const unsigned char*)(W1S + (size_t)g * 128 * 256);

        // ---- stage half 0 (k 0..127 = u columns), 32KB linear ----
        #pragma unroll
        for (int r = 0; r < 8; ++r) {
            int n = r * 16 + (t >> 4);
            async_cp16((unsigned char*)smem + r * 4096 + t * 16,
                       W1Sg + n * 512 + (t & 15) * 16);
        }
        // A-frags for half 0 (u-rows) — latency hidden behind staging drain
        s16x8 afr[4][2];
        #pragma unroll
        for (int ks = 0; ks < 4; ++ks)
            #pragma unroll
            for (int mt = 0; mt < 2; ++mt)
                afr[ks][mt] = *(const s16x8*)(urow[mt] + ks * 32 + quad * 8);

        f32x4 acc[2][8];
        #pragma unroll
        for (int mt = 0; mt < 2; ++mt)
            #pragma unroll
            for (int nt = 0; nt < 8; ++nt) acc[mt][nt] = (f32x4){0.f, 0.f, 0.f, 0.f};

        __syncthreads();   // drain: half-0 stage + u A-frags

        // ---- GEMM1 half 0 ----
        #pragma unroll
        for (int ks = 0; ks < 4; ++ks) {
            #pragma unroll
            for (int nt = 0; nt < 8; ++nt) {
                int gk = (ks * 4 + quad) ^ (n0 & 7);
                s16x8 bfrag = *(const s16x8*)(&W1s[(nt * 16 + n0) * 128 + gk * 8]);
                acc[0][nt] = __builtin_amdgcn_mfma_f32_16x16x32_bf16(afr[ks][0], bfrag, acc[0][nt], 0, 0, 0);
                acc[1][nt] = __builtin_amdgcn_mfma_f32_16x16x32_bf16(afr[ks][1], bfrag, acc[1][nt], 0, 0, 0);
            }
        }
        __syncthreads();   // half-0 reads done; buffer reusable

        // ---- stage half 1 (k 128..255 = v columns) into same buffer ----
        #pragma unroll
        for (int r = 0; r < 8; ++r) {
            int n = r * 16 + (t >> 4);
            async_cp16((unsigned char*)smem + r * 4096 + t * 16,
                       W1Sg + n * 512 + 256 + (t & 15) * 16);
        }
        // A-frags for half 1 (v-rows) — hidden behind this staging drain
        #pragma unroll
        for (int ks = 0; ks < 4; ++ks)
            #pragma unroll
            for (int mt = 0; mt < 2; ++mt)
                afr[ks][mt] = *(const s16x8*)(vrow[mt] + ks * 32 + quad * 8);

        __syncthreads();   // drain: half-1 stage + v A-frags

        // ---- GEMM1 half 1 ----
        #pragma unroll
        for (int ks = 0; ks < 4; ++ks) {
            #pragma unroll
            for (int nt = 0; nt < 8; ++nt) {
                int gk = (ks * 4 + quad) ^ (n0 & 7);
                s16x8 bfrag = *(const s16x8*)(&W1s[(nt * 16 + n0) * 128 + gk * 8]);
                acc[0][nt] = __builtin_amdgcn_mfma_f32_16x16x32_bf16(afr[ks][0], bfrag, acc[0][nt], 0, 0, 0);
                acc[1][nt] = __builtin_amdgcn_mfma_f32_16x16x32_bf16(afr[ks][1], bfrag, acc[1][nt], 0, 0, 0);
            }
        }
        __syncthreads();   // W1s dead; sH region writable

        // ---- LN constants (L1/L2-hot after first blocks) ----
        float b1v[8], lgv[8], lbv[8];
        #pragma unroll
        for (int nt = 0; nt < 8; ++nt) {
            int c = nt * 16 + n0;
            b1v[nt] = b1[g * HDIM + c];
            lgv[nt] = lng[g * HDIM + c];
            lbv[nt] = lnb[g * HDIM + c];
        }

        // ---- bias + LayerNorm + GELU; D layout: row = quad*4+reg, col = nt*16+n0 ----
        #pragma unroll
        for (int mt = 0; mt < 2; ++mt) {
            #pragma unroll
            for (int reg = 0; reg < 4; ++reg) {
                float s = 0.f, s2 = 0.f;
                float xv[8];
                #pragma unroll
                for (int nt = 0; nt < 8; ++nt) {
                    float x = acc[mt][nt][reg] + b1v[nt];
                    xv[nt] = x; s += x; s2 += x * x;
                }
                s  = row_sum16(s);      // DPP, no LDS pipe
                s2 = row_sum16(s2);
                float mu  = s  * (1.0f / HDIM);
                float var = s2 * (1.0f / HDIM) - mu * mu;
                float rs  = rsqrtf(var + 1e-5f);
                int m  = w * 32 + mt * 16 + quad * 4 + reg;
                int mx = m & 7;
                #pragma unroll
                for (int nt = 0; nt < 8; ++nt) {
                    float x = (xv[nt] - mu) * rs * lgv[nt] + lbv[nt];
                    x = gelu_exact(x);
                    int gsw = ((nt * 2 + (n0 >> 3)) ^ mx) << 3;   // swizzled col granule
                    sH[m * 128 + gsw + (n0 & 7)] = f2bf(x);
                }
            }
        }
        __syncthreads();

        // ---- GEMM2: h[128x128] x W2T[g][n=64][k=128], A from swizzled sH ----
        const unsigned short* W2Tg = W2T + (size_t)g * 64 * 128;
        f32x4 acc2[2][4];
        #pragma unroll
        for (int mt = 0; mt < 2; ++mt)
            #pragma unroll
            for (int nt2 = 0; nt2 < 4; ++nt2) acc2[mt][nt2] = (f32x4){0.f, 0.f, 0.f, 0.f};

        #pragma unroll
        for (int ks2 = 0; ks2 < 4; ++ks2) {
            s16x8 a2[2];
            #pragma unroll
            for (int mt = 0; mt < 2; ++mt) {
                int m = w * 32 + mt * 16 + n0;
                a2[mt] = *(const s16x8*)(&sH[m * 128 + (((ks2 * 4 + quad) ^ (m & 7)) << 3)]);
            }
            #pragma unroll
            for (int nt2 = 0; nt2 < 4; ++nt2) {
                s16x8 b2f = *(const s16x8*)(W2Tg + (size_t)(nt2 * 16 + n0) * 128 + ks2 * 32 + quad * 8);
                #pragma unroll
                for (int mt = 0; mt < 2; ++mt)
                    acc2[mt][nt2] = __builtin_amdgcn_mfma_f32_16x16x32_bf16(a2[mt], b2f, acc2[mt][nt2], 0, 0, 0);
            }
        }

        // ---- epilogue: GELU + dot W3 + DPP reduce + write ----
        {
            float b2v[4], w3v[4];
            #pragma unroll
            for (int nt2 = 0; nt2 < 4; ++nt2) {
                int c = nt2 * 16 + n0;
                b2v[nt2] = b2[g * 64 + c];
                w3v[nt2] = W3[g * 64 + c];
            }
            float bias3 = b3[g];
            int lo = (g == 0) ? 0   : (g == 1) ? gs1 : gs2;
            int hi = (g == 0) ? gs1 : (g == 1) ? gs2 : E;
            #pragma unroll
            for (int mt = 0; mt < 2; ++mt) {
                #pragma unroll
                for (int reg = 0; reg < 4; ++reg) {
                    float sacc = 0.f;
                    #pragma unroll
                    for (int nt2 = 0; nt2 < 4; ++nt2)
                        sacc += gelu_exact(acc2[mt][nt2][reg] + b2v[nt2]) * w3v[nt2];
                    sacc = row_sum16(sacc);
                    if (n0 == 0) {
                        int p = pos0 + w * 32 + mt * 16 + quad * 4 + reg;
                        if (p >= lo && p < hi) out[p] = sacc + bias3;
                    }
                }
            }
        }
        if (g < g1) __syncthreads();   // only boundary blocks loop again
    }
}

extern "C" void kernel_launch(void* const* d_in, const int* in_sizes, int n_in,
                              void* d_out, int out_size, void* d_ws, size_t ws_size,
                              hipStream_t stream) {
    const float* emb    = (const float*)d_in[0];
    const int*   edges  = (const int*)  d_in[1];
    const int*   groups = (const int*)  d_in[2];
    const float* W1     = (const float*)d_in[3];
    const float* b1     = (const float*)d_in[4];
    const float* lng    = (const float*)d_in[5];
    const float* lnb    = (const float*)d_in[6];
    const float* W2     = (const float*)d_in[7];
    const float* b2     = (const float*)d_in[8];
    const float* W3     = (const float*)d_in[9];
    const float* b3     = (const float*)d_in[10];
    float* out = (float*)d_out;
    int E        = in_sizes[2];
    int embElems = in_sizes[0];

    int nChunks = (E + 1023) / 1024;
    int embBlocks = (embElems / 8 + 255) / 256;

    // workspace layout
    unsigned short* embB = (unsigned short*)d_ws;
    unsigned short* W1S  = embB + (((size_t)embElems + 7) & ~(size_t)7);
    unsigned short* W2T  = W1S + (size_t)3 * 128 * 256;
    int* counts = (int*)(W2T + (size_t)3 * 64 * 128);
    int* bbase  = counts + (size_t)nChunks * 3;
    int* gstart = bbase  + (size_t)nChunks * 3;
    int* sorted = gstart + 4;

    k_prep   <<<dim3(embBlocks + 60 + nChunks), dim3(256), 0, stream>>>(
        emb, embElems, embBlocks, W1, W2, embB, W1S, W2T, groups, E, counts);
    k_scan   <<<dim3(1),       dim3(192), 0, stream>>>(counts, nChunks, bbase, gstart, E);
    k_scatter<<<dim3(nChunks), dim3(64),  0, stream>>>(groups, E, bbase, gstart, sorted);

    int nTiles = (E + TM - 1) / TM;
    k_mlp<<<dim3(nTiles), dim3(256), 0, stream>>>(
        embB, edges, sorted, gstart, W1S, b1, lng, lnb, W2T, b2, W3, b3, out, E);
}

// Round 8
// 296.174 us; speedup vs baseline: 1.7981x; 1.0868x over previous
//
#include <hip/hip_runtime.h>
#include <math.h>
#include <stdint.h>

#define HDIM 128
#define TM 64   // edges per block (4 waves, 16 edges per wave, 1 m-tile)

typedef short s16x8 __attribute__((ext_vector_type(8)));      // 8 bf16 (4 VGPRs) MFMA A/B frag
typedef float f32x4 __attribute__((ext_vector_type(4)));      // MFMA C/D frag
typedef unsigned short ushort8 __attribute__((ext_vector_type(8)));

// fp32 -> bf16 round-to-nearest-even
__device__ __forceinline__ unsigned short f2bf(float x) {
    unsigned u = __float_as_uint(x);
    u += 0x7FFFu + ((u >> 16) & 1u);
    return (unsigned short)(u >> 16);
}

// Abramowitz-Stegun 7.1.26: |err| <= 1.5e-7 absolute.
__device__ __forceinline__ float erf_fast(float x) {
    float ax = fabsf(x);
    float t = __builtin_amdgcn_rcpf(fmaf(0.3275911f, ax, 1.0f));
    float p =        fmaf(t, 1.061405429f, -1.453152027f);
    p = fmaf(t, p, 1.421413741f);
    p = fmaf(t, p, -0.284496736f);
    p = fmaf(t, p, 0.254829592f);
    float e = exp2f(ax * ax * -1.4426950408889634f);
    float r = 1.0f - p * t * e;
    return copysignf(r, x);
}

__device__ __forceinline__ float gelu_exact(float x) {
    return 0.5f * x * (1.0f + erf_fast(x * 0.70710678118654752440f));
}

// 16-lane (DPP row) sum via row_ror rotations: full-rate VALU, no LDS pipe.
template <int N>
__device__ __forceinline__ float rot_add(float v) {
    int r = __builtin_amdgcn_update_dpp(0, __float_as_int(v), 0x120 | N, 0xF, 0xF, false);
    return v + __int_as_float(r);
}
__device__ __forceinline__ float row_sum16(float v) {
    v = rot_add<1>(v); v = rot_add<2>(v); v = rot_add<4>(v); v = rot_add<8>(v);
    return v;
}

// async global->LDS 16B per lane; LDS dst must be wave-uniform base + lane*16
__device__ __forceinline__ void async_cp16(void* lds_dst, const void* g_src) {
    __builtin_amdgcn_global_load_lds(
        (const __attribute__((address_space(1))) unsigned int*)g_src,
        (__attribute__((address_space(3))) unsigned int*)lds_dst,
        16, 0, 0);
}

// ---------------- stable counting-sort: scan + scatter ----------------

__global__ void k_scan(const int* __restrict__ counts, int nChunks,
                       int* __restrict__ bbase, int* __restrict__ gstart, int E) {
    __shared__ int tot[3];
    int t = threadIdx.x;         // block = 192
    int lane = t & 63;
    int g = t >> 6;              // 0..2
    int carry = 0;
    for (int base = 0; base < nChunks; base += 64) {
        int b = base + lane;
        int v = (b < nChunks) ? counts[b * 3 + g] : 0;
        int sc = v;
        #pragma unroll
        for (int off = 1; off < 64; off <<= 1) {
            int u = __shfl_up(sc, off);
            if (lane >= off) sc += u;
        }
        if (b < nChunks) bbase[b * 3 + g] = carry + sc - v;
        carry += __shfl(sc, 63);
    }
    if (lane == 0) tot[g] = carry;
    __syncthreads();
    if (t == 0) {
        gstart[0] = 0;
        gstart[1] = tot[0];
        gstart[2] = tot[0] + tot[1];
        gstart[3] = E;
    }
}

__global__ void k_scatter(const int* __restrict__ groups, int E,
                          const int* __restrict__ bbase, const int* __restrict__ gstart,
                          int* __restrict__ sorted) {
    int b = blockIdx.x;
    int lane = threadIdx.x;  // block = 64 (one wave)
    int run0 = gstart[0] + bbase[b * 3 + 0];
    int run1 = gstart[1] + bbase[b * 3 + 1];
    int run2 = gstart[2] + bbase[b * 3 + 2];
    unsigned long long lt = (1ull << lane) - 1ull;
    for (int p = 0; p < 16; ++p) {
        int e = b * 1024 + p * 64 + lane;
        int g = (e < E) ? groups[e] : 3;
        unsigned long long m0 = __ballot(g == 0);
        unsigned long long m1 = __ballot(g == 1);
        unsigned long long m2 = __ballot(g == 2);
        int pos = 0;
        if (g == 0) pos = run0 + __popcll(m0 & lt);
        else if (g == 1) pos = run1 + __popcll(m1 & lt);
        else if (g == 2) pos = run2 + __popcll(m2 & lt);
        if (e < E) sorted[pos] = e;
        run0 += __popcll(m0);
        run1 += __popcll(m1);
        run2 += __popcll(m2);
    }
}

// ---------------- prep (fused with histogram) ----------------
// W1S layout: [g][n][half][h'][8] shorts, half = k/128, h = (k/8)%16, h' = h ^ (n&7).
// W2T[g][n=64][k=128].
__global__ void k_prep(const float* __restrict__ emb, int embElems, int embBlocks,
                       const float* __restrict__ W1, const float* __restrict__ W2,
                       unsigned short* __restrict__ embB,
                       unsigned short* __restrict__ W1S, unsigned short* __restrict__ W2T,
                       const int* __restrict__ groups, int E, int* __restrict__ counts) {
    if ((int)blockIdx.x >= embBlocks + 60) {
        // histogram part
        __shared__ int c[3];
        int t = threadIdx.x;
        int blk = blockIdx.x - (embBlocks + 60);
        if (t < 3) c[t] = 0;
        __syncthreads();
        int base = blk * 1024;
        for (int i = t; i < 1024; i += 256) {
            int e = base + i;
            if (e < E) atomicAdd(&c[groups[e]], 1);
        }
        __syncthreads();
        if (t < 3) counts[blk * 3 + t] = c[t];
        return;
    }
    if ((int)blockIdx.x < embBlocks) {
        int i = (blockIdx.x * 256 + threadIdx.x) * 8;
        if (i + 8 <= embElems) {
            float4 a = *(const float4*)(emb + i);
            float4 b = *(const float4*)(emb + i + 4);
            ushort8 o;
            o[0] = f2bf(a.x); o[1] = f2bf(a.y); o[2] = f2bf(a.z); o[3] = f2bf(a.w);
            o[4] = f2bf(b.x); o[5] = f2bf(b.y); o[6] = f2bf(b.z); o[7] = f2bf(b.w);
            *(ushort8*)(embB + i) = o;
        } else {
            for (int j = i; j < embElems; ++j) embB[j] = f2bf(emb[j]);
        }
        return;
    }
    int idx = (blockIdx.x - embBlocks) * 256 + threadIdx.x;
    if (idx < 3 * 32 * 128) {                    // W1S: task = (g, gk, n)
        int g  = idx >> 12;
        int r  = idx & 4095;
        int gk = r >> 7;                         // global k-granule 0..31 (k0 = gk*8)
        int n  = r & 127;
        const float* src = W1 + ((size_t)g * 256 + gk * 8) * 128 + n;
        ushort8 o;
        #pragma unroll
        for (int j = 0; j < 8; ++j) o[j] = f2bf(src[j * 128]);
        int half = gk >> 4;
        int hs   = (gk & 15) ^ (n & 7);          // bank swizzle within half
        *(ushort8*)(W1S + (((size_t)(g * 128 + n) * 2 + half) * 16 + hs) * 8) = o;
    } else if (idx < 3 * 32 * 128 + 3 * 16 * 64) {
        int r2 = idx - 3 * 32 * 128;             // W2T[g][n=64][k=128]
        int g  = r2 >> 10;
        int r  = r2 & 1023;
        int kc = r >> 6;
        int n  = r & 63;
        const float* src = W2 + (size_t)g * 128 * 64 + (size_t)(kc * 8) * 64 + n;
        ushort8 o;
        #pragma unroll
        for (int j = 0; j < 8; ++j) o[j] = f2bf(src[j * 64]);
        *(ushort8*)(W2T + ((size_t)(g * 64 + n)) * 128 + kc * 8) = o;
    }
}

// ---------------- fused per-edge MLP ----------------
// Block: 256 thr = 4 waves; TM=64 edges, 16 per wave (ONE m-tile -> acc 32 regs,
// afr 16 regs; total ~100 regs/thread -> 4-5 waves/SIMD, no spills).
// GEMM1 K-split: stage W1 half-k (32KB) -> MFMA (u-rows) -> restage -> MFMA (v-rows).
// sH (swizzled 64x128 bf16 = 16KB) overlays. Total LDS = 32KB -> 4-5 blocks/CU.
// 16-lane reductions via DPP row_ror.
__global__ __launch_bounds__(256, 2)
void k_mlp(const unsigned short* __restrict__ embB,
           const int* __restrict__ edges,
           const int* __restrict__ sorted,
           const int* __restrict__ gstart,
           const unsigned short* __restrict__ W1S,
           const float* __restrict__ b1,
           const float* __restrict__ lng, const float* __restrict__ lnb,
           const unsigned short* __restrict__ W2T,
           const float* __restrict__ b2,
           const float* __restrict__ W3, const float* __restrict__ b3,
           float* __restrict__ out, int E)
{
    __shared__ __align__(16) unsigned short smem[16384];   // 32768 B
    unsigned short* W1s = smem;   // staged half: [128 n][16 granule][8]
    unsigned short* sH  = smem;   // [64 m][128 c] swizzled bf16 (16KB), after GEMM1

    const int t    = threadIdx.x;
    const int w    = t >> 6;        // wave 0..3
    const int lane = t & 63;
    const int n0   = lane & 15;     // MFMA 16-index
    const int quad = lane >> 4;     // MFMA k-quad / D row-group

    const int pos0 = blockIdx.x * TM;

    int gs1 = gstart[1], gs2 = gstart[2];
    int plast = (pos0 + TM - 1 < E) ? pos0 + TM - 1 : E - 1;
    int g0 = (pos0  >= gs2) ? 2 : (pos0  >= gs1) ? 1 : 0;
    int g1 = (plast >= gs2) ? 2 : (plast >= gs1) ? 1 : 0;

    // this lane's edge (row m = n0 within the wave's 16-edge tile)
    int p_lane = pos0 + w * 16 + n0;
    int pc = p_lane < E ? p_lane : E - 1;
    int e  = sorted[pc];
    const unsigned short* urow = embB + (size_t)edges[2 * e]     * HDIM;
    const unsigned short* vrow = embB + (size_t)edges[2 * e + 1] * HDIM;

    for (int g = g0; g <= g1; ++g) {
        const unsigned char* W1Sg = (const unsigned char*)(W1S + (size_t)g * 128 * 256);

        // ---- stage half 0 (k 0..127 = u columns), 32KB linear ----
        #pragma unroll
        for (int r = 0; r < 8; ++r)
            async_cp16((unsigned char*)smem + r * 4096 + t * 16,
                       W1Sg + (r * 16 + (t >> 4)) * 512 + (t & 15) * 16);

        // A-frags half 0 (u-row) — hidden behind the staging drain
        s16x8 afr[4];
        #pragma unroll
        for (int ks = 0; ks < 4; ++ks)
            afr[ks] = *(const s16x8*)(urow + ks * 32 + quad * 8);

        f32x4 acc[8];
        #pragma unroll
        for (int nt = 0; nt < 8; ++nt) acc[nt] = (f32x4){0.f, 0.f, 0.f, 0.f};

        __syncthreads();   // drain: half-0 stage + u A-frags

        #pragma unroll
        for (int ks = 0; ks < 4; ++ks) {
            #pragma unroll
            for (int nt = 0; nt < 8; ++nt) {
                int gk = (ks * 4 + quad) ^ (n0 & 7);
                s16x8 bfrag = *(const s16x8*)(&W1s[(nt * 16 + n0) * 128 + gk * 8]);
                acc[nt] = __builtin_amdgcn_mfma_f32_16x16x32_bf16(afr[ks], bfrag, acc[nt], 0, 0, 0);
            }
        }
        __syncthreads();   // half-0 reads done; buffer reusable

        // ---- stage half 1 (k 128..255 = v columns) into same buffer ----
        #pragma unroll
        for (int r = 0; r < 8; ++r)
            async_cp16((unsigned char*)smem + r * 4096 + t * 16,
                       W1Sg + (r * 16 + (t >> 4)) * 512 + 256 + (t & 15) * 16);

        #pragma unroll
        for (int ks = 0; ks < 4; ++ks)
            afr[ks] = *(const s16x8*)(vrow + ks * 32 + quad * 8);

        __syncthreads();   // drain: half-1 stage + v A-frags

        #pragma unroll
        for (int ks = 0; ks < 4; ++ks) {
            #pragma unroll
            for (int nt = 0; nt < 8; ++nt) {
                int gk = (ks * 4 + quad) ^ (n0 & 7);
                s16x8 bfrag = *(const s16x8*)(&W1s[(nt * 16 + n0) * 128 + gk * 8]);
                acc[nt] = __builtin_amdgcn_mfma_f32_16x16x32_bf16(afr[ks], bfrag, acc[nt], 0, 0, 0);
            }
        }
        __syncthreads();   // W1s dead; sH region writable

        // ---- LN constants (loaded after afr dead; L1-hot) ----
        float b1v[8], lgv[8], lbv[8];
        #pragma unroll
        for (int nt = 0; nt < 8; ++nt) {
            int c = nt * 16 + n0;
            b1v[nt] = b1[g * HDIM + c];
            lgv[nt] = lng[g * HDIM + c];
            lbv[nt] = lnb[g * HDIM + c];
        }

        // ---- bias + LayerNorm + GELU; D layout: row = quad*4+reg, col = nt*16+n0 ----
        #pragma unroll
        for (int reg = 0; reg < 4; ++reg) {
            float s = 0.f, s2 = 0.f;
            float xv[8];
            #pragma unroll
            for (int nt = 0; nt < 8; ++nt) {
                float x = acc[nt][reg] + b1v[nt];
                xv[nt] = x; s += x; s2 += x * x;
            }
            s  = row_sum16(s);
            s2 = row_sum16(s2);
            float mu  = s  * (1.0f / HDIM);
            float var = s2 * (1.0f / HDIM) - mu * mu;
            float rs  = rsqrtf(var + 1e-5f);
            int m  = w * 16 + quad * 4 + reg;
            int mx = m & 7;
            #pragma unroll
            for (int nt = 0; nt < 8; ++nt) {
                float x = (xv[nt] - mu) * rs * lgv[nt] + lbv[nt];
                x = gelu_exact(x);
                int gsw = ((nt * 2 + (n0 >> 3)) ^ mx) << 3;   // swizzled col granule
                sH[m * 128 + gsw + (n0 & 7)] = f2bf(x);
            }
        }
        __syncthreads();

        // ---- GEMM2: h[64x128] x W2T[g][n=64][k=128], A from swizzled sH ----
        const unsigned short* W2Tg = W2T + (size_t)g * 64 * 128;
        f32x4 acc2[4];
        #pragma unroll
        for (int nt2 = 0; nt2 < 4; ++nt2) acc2[nt2] = (f32x4){0.f, 0.f, 0.f, 0.f};

        #pragma unroll
        for (int ks2 = 0; ks2 < 4; ++ks2) {
            int m = w * 16 + n0;
            s16x8 a2 = *(const s16x8*)(&sH[m * 128 + (((ks2 * 4 + quad) ^ (m & 7)) << 3)]);
            #pragma unroll
            for (int nt2 = 0; nt2 < 4; ++nt2) {
                s16x8 b2f = *(const s16x8*)(W2Tg + (size_t)(nt2 * 16 + n0) * 128 + ks2 * 32 + quad * 8);
                acc2[nt2] = __builtin_amdgcn_mfma_f32_16x16x32_bf16(a2, b2f, acc2[nt2], 0, 0, 0);
            }
        }

        // ---- epilogue: GELU + dot W3 + DPP reduce + write ----
        {
            float b2v[4], w3v[4];
            #pragma unroll
            for (int nt2 = 0; nt2 < 4; ++nt2) {
                int c = nt2 * 16 + n0;
                b2v[nt2] = b2[g * 64 + c];
                w3v[nt2] = W3[g * 64 + c];
            }
            float bias3 = b3[g];
            int lo = (g == 0) ? 0   : (g == 1) ? gs1 : gs2;
            int hi = (g == 0) ? gs1 : (g == 1) ? gs2 : E;
            #pragma unroll
            for (int reg = 0; reg < 4; ++reg) {
                float sacc = 0.f;
                #pragma unroll
                for (int nt2 = 0; nt2 < 4; ++nt2)
                    sacc += gelu_exact(acc2[nt2][reg] + b2v[nt2]) * w3v[nt2];
                sacc = row_sum16(sacc);
                if (n0 == 0) {
                    int p = pos0 + w * 16 + quad * 4 + reg;
                    if (p >= lo && p < hi) out[p] = sacc + bias3;
                }
            }
        }
        if (g < g1) __syncthreads();   // only boundary blocks loop again
    }
}

extern "C" void kernel_launch(void* const* d_in, const int* in_sizes, int n_in,
                              void* d_out, int out_size, void* d_ws, size_t ws_size,
                              hipStream_t stream) {
    const float* emb    = (const float*)d_in[0];
    const int*   edges  = (const int*)  d_in[1];
    const int*   groups = (const int*)  d_in[2];
    const float* W1     = (const float*)d_in[3];
    const float* b1     = (const float*)d_in[4];
    const float* lng    = (const float*)d_in[5];
    const float* lnb    = (const float*)d_in[6];
    const float* W2     = (const float*)d_in[7];
    const float* b2     = (const float*)d_in[8];
    const float* W3     = (const float*)d_in[9];
    const float* b3     = (const float*)d_in[10];
    float* out = (float*)d_out;
    int E        = in_sizes[2];
    int embElems = in_sizes[0];

    int nChunks = (E + 1023) / 1024;
    int embBlocks = (embElems / 8 + 255) / 256;

    // workspace layout
    unsigned short* embB = (unsigned short*)d_ws;
    unsigned short* W1S  = embB + (((size_t)embElems + 7) & ~(size_t)7);
    unsigned short* W2T  = W1S + (size_t)3 * 128 * 256;
    int* counts = (int*)(W2T + (size_t)3 * 64 * 128);
    int* bbase  = counts + (size_t)nChunks * 3;
    int* gstart = bbase  + (size_t)nChunks * 3;
    int* sorted = gstart + 4;

    k_prep   <<<dim3(embBlocks + 60 + nChunks), dim3(256), 0, stream>>>(
        emb, embElems, embBlocks, W1, W2, embB, W1S, W2T, groups, E, counts);
    k_scan   <<<dim3(1),       dim3(192), 0, stream>>>(counts, nChunks, bbase, gstart, E);
    k_scatter<<<dim3(nChunks), dim3(64),  0, stream>>>(groups, E, bbase, gstart, sorted);

    int nTiles = (E + TM - 1) / TM;
    k_mlp<<<dim3(nTiles), dim3(256), 0, stream>>>(
        embB, edges, sorted, gstart, W1S, b1, lng, lnb, W2T, b2, W3, b3, out, E);
}